// Round 11
// baseline (69.327 us; speedup 1.0000x reference)
//
#include <hip/hip_runtime.h>

// BSHConv3D as ONE im2col GEMM, round 11: NO-LDS direct-load GEMM.
// Math/table unchanged (K=32 MFMA, transposed, padded-fp16 Xp in d_ws).
// KEY: B-fragment (lane: voxel=lr, kchunk=kg; t) == ONE contiguous 16B cell
// of Xp at kernel tap k=4t+kg  ->  per-lane global_load_dwordx4 directly,
// no im2col, no LDS, no barriers. 8-wave redundancy now absorbed by L1/L2
// (per-tile window 7.2KB << 32KB L1), overlapping the HBM store drain.
// Persistent blocks: grid 768 = 2 col-halves x 384; block owns 6 h-rows x 48 w
// (18 slices of 16 voxels), af table frags loaded once.
// Tiers: t6 (table+Xp, ~2.23 MB ws) > t3 (229 KB) > fb (24 KB).

typedef _Float16 half8_t __attribute__((ext_vector_type(8)));
typedef float floatx4 __attribute__((ext_vector_type(4)));

#define TB_SLOTS (7 * 32 * 64)                 // 14336 uint4 slots
#define TBL_BYTES (TB_SLOTS * 16)              // 229376
#define XP_OFF   TBL_BYTES
#define XP_BYTES (50 * 50 * 50 * 16)           // 2,000,000
#define BIAS_OFF (XP_OFF + XP_BYTES)
#define WS_T6_BYTES (BIAS_OFF + 16)            // 2,229,392
#define WS_T3_BYTES TBL_BYTES

typedef __attribute__((address_space(1))) const unsigned int gq_t;
typedef __attribute__((address_space(3))) unsigned int lq_t;

__device__ inline unsigned short f2h(float v) {
    return __builtin_bit_cast(unsigned short, (_Float16)v);
}
__device__ inline unsigned pk2(float a, float b) {
    return (unsigned)f2h(a) | ((unsigned)f2h(b) << 16);
}

// ---------------- table precompute (unchanged) ----------------
__global__ __launch_bounds__(512) void bsh_precompute_gemm(
    const float* __restrict__ AR,  // [27,2,16]
    const float* __restrict__ AI,  // [27,2,16]
    const float* __restrict__ Wgt, // [8,16,2,4]
    const float* __restrict__ WC,  // [8,16]
    const float* __restrict__ Bc,  // [16]
    uint4* __restrict__ TB)
{
    int s = blockIdx.x * 512 + threadIdx.x;
    if (s >= TB_SLOTS) return;
    int l = s & 63, ot = (s >> 6) & 31, t = s >> 11;
    int col = 16 * ot + (l & 15);
    int f = col >> 5, n = (col >> 1) & 15, ri = col & 1;
    int dg = (n >= 9) ? 3 : (n >= 4) ? 2 : (n >= 1) ? 1 : 0;
    const float* atom = ri ? AI : AR;
    float vj[8];
    #pragma unroll
    for (int j = 0; j < 8; ++j) {
        int kap = 32 * t + 8 * (l >> 4) + j;
        int k = kap >> 3, c = kap & 7;
        float v = 0.f;
        if (k < 27) {
            float w0 = Wgt[((c * 16 + f) * 2 + 0) * 4 + dg];
            float w1 = Wgt[((c * 16 + f) * 2 + 1) * 4 + dg];
            v = atom[k * 32 + n] * w0 + atom[k * 32 + 16 + n] * w1;
            if (k == 13 && n == 0 && ri == 0) v += WC[c * 16 + f];
        } else {
            if (c == 7 && n == 0 && ri == 0) v = Bc[f];
        }
        vj[j] = v;
    }
    TB[s] = make_uint4(pk2(vj[0], vj[1]), pk2(vj[2], vj[3]),
                       pk2(vj[4], vj[5]), pk2(vj[6], vj[7]));
}

// ---------------- Xp: padded fp16 copy of X (unchanged) ----------------
__global__ __launch_bounds__(512) void bsh_xp(
    const float* __restrict__ X, char* __restrict__ WSB)
{
    int idx = blockIdx.x * 512 + threadIdx.x;
    if (idx == 0)
        *(uint4*)(WSB + BIAS_OFF) = make_uint4(0u, 0u, 0u, 0x3C000000u); // 1.0h at c7
    if (idx >= 125000) return;
    int dd = idx / 2500, rem = idx - dd * 2500;
    int hh = rem / 50, ww = rem - hh * 50;
    unsigned x01 = 0, x23 = 0, x45 = 0, x67 = 0;
    if (dd >= 1 && dd <= 48 && hh >= 1 && hh <= 48 && ww >= 1 && ww <= 48) {
        const float* px = &X[((((dd - 1) * 48) + (hh - 1)) * 48 + (ww - 1)) * 8];
        float4 a = *(const float4*)px;
        float4 b = *(const float4*)(px + 4);
        x01 = pk2(a.x, a.y); x23 = pk2(a.z, a.w);
        x45 = pk2(b.x, b.y); x67 = pk2(b.z, b.w);
    }
    *(uint4*)(WSB + XP_OFF + (size_t)idx * 16) = make_uint4(x01, x23, x45, x67);
}

// ---------------- main GEMM kernel (t6, no-LDS direct-load) ----------------
__global__ __launch_bounds__(512) void bsh_gemm_t6(
    const char* __restrict__ WSB,
    float* __restrict__ Out)       // [110592,512]
{
    const int tid = threadIdx.x;
    const int bid = blockIdx.x;
    const int nb = bid & 1;          // col half (256 outcols)
    const int m  = bid >> 1;         // 0..383
    const int g3 = m * 3;            // first tile (of 3)
    const int d  = g3 / 24;
    const int hbase = 2 * (g3 - 24 * d);   // 6 h-rows: hbase..hbase+5

    const uint4* TB = (const uint4*)WSB;
    const char*  Xp = WSB + XP_OFF;

    const int lane = tid & 63, cg = tid >> 6;   // 8 waves = 8 col-groups of 32
    const int kg = lane >> 4, lr = lane & 15;

    // ---- A-frags (table): 14 uint4, loaded once ----
    const uint4* ap = TB + ((size_t)(nb * 16 + cg * 2) * 64 + lane);
    uint4 af0[7], af1[7];
    #pragma unroll
    for (int t = 0; t < 7; ++t) {
        af0[t] = ap[(size_t)(t * 32 + 0) * 64];
        af1[t] = ap[(size_t)(t * 32 + 1) * 64];
    }

    // ---- per-lane tap byte-offsets ko[t] for k = 4t+kg (slice-invariant) ----
    int ko[7];
    #pragma unroll
    for (int t = 0; t < 7; ++t) {
        int k = 4 * t + kg;
        if (k > 27) k = 27;          // only (kg=3,t=6) hits 27; replaced below anyway
        int kz = k / 9, r9 = k - 9 * kz;
        int ky = r9 / 3, kx = r9 - 3 * ky;
        ko[t] = (kz * 2500 + ky * 50 + kx) * 16;
    }
    const bool isbias = (kg == 3);   // t==6 tap is the bias cell for kg==3

    // ---- 18 slices: h = hbase + hs, w = 16*ws2 + lr ----
    #pragma unroll 1
    for (int hs = 0; hs < 6; ++hs) {
        const int h = hbase + hs;
        const int rowvoff = (d * 2500 + h * 50 + lr) * 16;
        #pragma unroll 1
        for (int ws2 = 0; ws2 < 3; ++ws2) {
            const int sb = rowvoff + ws2 * 256;     // slice base voffset
            uint4 b[7];
            #pragma unroll
            for (int t = 0; t < 7; ++t) {
                int off = sb + ko[t];
                if (t == 6 && isbias) off = XP_BYTES;   // bias cell (k=27)
                b[t] = *(const uint4*)(Xp + off);
            }
            floatx4 a0 = (floatx4){0.f, 0.f, 0.f, 0.f};
            floatx4 a1 = (floatx4){0.f, 0.f, 0.f, 0.f};
            #pragma unroll
            for (int t = 0; t < 7; ++t)
                a0 = __builtin_amdgcn_mfma_f32_16x16x32_f16(
                         __builtin_bit_cast(half8_t, af0[t]),
                         __builtin_bit_cast(half8_t, b[t]), a0, 0, 0, 0);
            #pragma unroll
            for (int t = 0; t < 7; ++t)
                a1 = __builtin_amdgcn_mfma_f32_16x16x32_f16(
                         __builtin_bit_cast(half8_t, af1[t]),
                         __builtin_bit_cast(half8_t, b[t]), a1, 0, 0, 0);

            float* ob = Out + (size_t)((d * 48 + h) * 48 + ws2 * 16 + lr) * 512
                            + nb * 256 + cg * 32 + 4 * kg;
            *(floatx4*)ob        = a0;
            *(floatx4*)(ob + 16) = a1;
        }
    }
}

// ---------------- t3 path (round-8 kernel, table-only ws) ----------------
__global__ __launch_bounds__(512) void bsh_gemm_t3(
    const float* __restrict__ X,
    const uint4* __restrict__ TB,
    float* __restrict__ Out)
{
    __shared__ _Float16 B_lds[96 * 232];

    const int tid = threadIdx.x;
    const int bid = blockIdx.x;
    const int nb = bid & 1;
    const int rb = bid >> 1;
    const int d  = rb / 24;
    const int hp = rb - 24 * d;

    const int lane = tid & 63, cg = tid >> 6;
    const int kg = lane >> 4, lr = lane & 15;

    const uint4* ap = TB + ((size_t)(nb * 16 + cg * 2) * 64 + lane);
    uint4 af[2][7];
    #pragma unroll
    for (int t = 0; t < 7; ++t) {
        af[0][t] = ap[(size_t)(t * 32 + 0) * 64];
        af[1][t] = ap[(size_t)(t * 32 + 1) * 64];
    }

    #pragma unroll
    for (int i = 0; i < 6; ++i) {
        int cell = tid + i * 512;
        if (cell < 2688) {
            int k = cell / 96;
            int v = cell - 96 * k;
            unsigned x01 = 0, x23 = 0, x45 = 0, x67 = 0;
            if (k == 27) {
                x67 = 0x3C000000u;
            } else {
                int kz = k / 9, r9 = k - 9 * kz;
                int ky = r9 / 3, kx = r9 - 3 * ky;
                int hl = (v >= 48) ? 1 : 0;
                int dd = d - 1 + kz;
                int hh = 2 * hp + hl - 1 + ky;
                int ww = v - 48 * hl - 1 + kx;
                if ((unsigned)dd < 48u && (unsigned)hh < 48u && (unsigned)ww < 48u) {
                    const float* px = &X[(((dd * 48 + hh) * 48) + ww) * 8];
                    float4 a = *(const float4*)px;
                    float4 b = *(const float4*)(px + 4);
                    x01 = pk2(a.x, a.y); x23 = pk2(a.z, a.w);
                    x45 = pk2(b.x, b.y); x67 = pk2(b.z, b.w);
                }
            }
            char* wp = (char*)B_lds + v * 464 + k * 16;
            *(uint2*)wp       = make_uint2(x01, x23);
            *(uint2*)(wp + 8) = make_uint2(x45, x67);
        }
    }
    __syncthreads();

    const char* bbase = (const char*)B_lds + lr * 464 + kg * 16;

    #pragma unroll 1
    for (int vt = 0; vt < 6; ++vt) {
        const char* brow = bbase + (size_t)vt * 16 * 464;
        half8_t b[7];
        #pragma unroll
        for (int t = 0; t < 7; ++t)
            b[t] = *(const half8_t*)(brow + 64 * t);

        floatx4 a0 = (floatx4){0.f, 0.f, 0.f, 0.f};
        floatx4 a1 = (floatx4){0.f, 0.f, 0.f, 0.f};
        #pragma unroll
        for (int t = 0; t < 7; ++t)
            a0 = __builtin_amdgcn_mfma_f32_16x16x32_f16(
                     __builtin_bit_cast(half8_t, af[0][t]), b[t], a0, 0, 0, 0);
        #pragma unroll
        for (int t = 0; t < 7; ++t)
            a1 = __builtin_amdgcn_mfma_f32_16x16x32_f16(
                     __builtin_bit_cast(half8_t, af[1][t]), b[t], a1, 0, 0, 0);

        float* ob = Out + (size_t)(rb * 96 + vt * 16 + lr) * 512
                        + nb * 256 + cg * 32 + 4 * kg;
        *(floatx4*)ob        = a0;
        *(floatx4*)(ob + 16) = a1;
    }
}

// ================= fallback path (round-2 kernel, 24 KB ws) =================
#define FB_NBLK (48*48*6)
#define FB_WS_FLOATS 5968

__global__ __launch_bounds__(512) void fb_precompute(
    const float* __restrict__ AR, const float* __restrict__ AI,
    const float* __restrict__ Wgt, const float* __restrict__ WC,
    const float* __restrict__ Bc, float* __restrict__ T)
{
    const int tid = threadIdx.x;
    for (int i = tid; i < 4096; i += 512) {
        int row = i >> 4, f = row >> 4, n = row & 15;
        int pc = (i >> 2) & 3, e = i & 3;
        int chunk = pc ^ (n & 3);
        int cr = chunk * 4 + e, c = cr >> 1, r = cr & 1;
        int dg = (n >= 9) ? 3 : (n >= 4) ? 2 : (n >= 1) ? 1 : 0;
        T[i] = Wgt[c * 128 + f * 8 + r * 4 + dg];
    }
    for (int i = tid; i < 1728; i += 512) {
        int k = i >> 6, n = (i >> 2) & 15, q = i & 3;
        const float* src = (q >> 1) ? AI : AR;
        T[4096 + i] = src[k * 32 + (q & 1) * 16 + n];
    }
    if (tid < 128) T[5824 + tid] = WC[(tid & 7) * 16 + (tid >> 3)];
    if (tid < 16)  T[5952 + tid] = Bc[tid];
}

__device__ inline float4 fb_shfl_xor4(float4 v, int m) {
    return make_float4(__shfl_xor(v.x, m), __shfl_xor(v.y, m),
                       __shfl_xor(v.z, m), __shfl_xor(v.w, m));
}

__global__ __launch_bounds__(512) void fb_kernel(
    const float* __restrict__ X, const float* __restrict__ T,
    float* __restrict__ Out)
{
    __shared__ float cst[FB_WS_FLOATS];
    __shared__ float x_lds[720];

    const int tid = threadIdx.x;
    const int bid = blockIdx.x;
    const int d  = bid / (48 * 6);
    const int r0 = bid - d * (48 * 6);
    const int h  = r0 / 6;
    const int w0 = (r0 - h * 6) * 8;

    {
        const float4* t4 = (const float4*)T;
        float4* c4 = (float4*)cst;
        #pragma unroll
        for (int i = 0; i < 3; ++i) {
            int idx = tid + i * 512;
            if (idx < FB_WS_FLOATS / 4) c4[idx] = t4[idx];
        }
        if (tid < 180) {
            int r3 = tid / 20, rem = tid - r3 * 20;
            int wx = rem >> 1, c0 = (rem & 1) * 4;
            int dz = r3 / 3, dy = r3 - dz * 3;
            int dd = d - 1 + dz, hh = h - 1 + dy, ww = w0 - 1 + wx;
            float4 v = make_float4(0.f, 0.f, 0.f, 0.f);
            if ((unsigned)dd < 48u && (unsigned)hh < 48u && (unsigned)ww < 48u)
                v = *(const float4*)&X[(((dd * 48 + hh) * 48 + ww) * 8) + c0];
            *(float4*)&x_lds[tid * 4] = v;
        }
    }
    __syncthreads();

    const int wave = tid >> 6, lane = tid & 63;
    const int n = lane & 15, g = lane >> 4;
    const float* atoms_lds = cst + 4096;
    const float* wc_lds    = cst + 5824;
    const float* b_lds     = cst + 5952;

    float sr0 = 0, sr1 = 0, sr2 = 0, sr3 = 0;
    float si0 = 0, si1 = 0, si2 = 0, si3 = 0;
    #pragma unroll
    for (int kz = 0; kz < 3; ++kz)
    #pragma unroll
    for (int ky = 0; ky < 3; ++ky)
    #pragma unroll
    for (int kx = 0; kx < 3; ++kx) {
        const int k = (kz * 3 + ky) * 3 + kx;
        const float2 xv = *(const float2*)&x_lds[(((kz * 3 + ky) * 10) + wave + kx) * 8 + 2 * g];
        const float4 a  = *(const float4*)&atoms_lds[k * 64 + n * 4];
        sr0 += xv.x * a.x; sr1 += xv.x * a.y;
        sr2 += xv.y * a.x; sr3 += xv.y * a.y;
        si0 += xv.x * a.z; si1 += xv.x * a.w;
        si2 += xv.y * a.z; si3 += xv.y * a.w;
    }
    const float4 sR0 = make_float4(sr0, sr1, sr2, sr3);
    const float4 sI0 = make_float4(si0, si1, si2, si3);
    const float4 sR1 = fb_shfl_xor4(sR0, 16), sI1 = fb_shfl_xor4(sI0, 16);
    const float4 sR2 = fb_shfl_xor4(sR0, 32), sI2 = fb_shfl_xor4(sI0, 32);
    const float4 sR3 = fb_shfl_xor4(sR1, 32), sI3 = fb_shfl_xor4(sI1, 32);

    float cent[4];
    {
        const int cb = ((1 * 3 + 1) * 10 + wave + 1) * 8;
        const float4 xc0 = *(const float4*)&x_lds[cb];
        const float4 xc1 = *(const float4*)&x_lds[cb + 4];
        #pragma unroll
        for (int fi = 0; fi < 4; ++fi) {
            const int f = 4 * g + fi;
            const float* wcr = &wc_lds[f * 8];
            cent[fi] = b_lds[f]
                + xc0.x * wcr[0] + xc0.y * wcr[1] + xc0.z * wcr[2] + xc0.w * wcr[3]
                + xc1.x * wcr[4] + xc1.y * wcr[5] + xc1.z * wcr[6] + xc1.w * wcr[7];
        }
    }

    const float4* w4 = (const float4*)cst;
    const int gx = g ^ (n & 3);
    const int out_base = ((d * 48 + h) * 48 + (w0 + wave)) * 512;
    #pragma unroll
    for (int fi = 0; fi < 4; ++fi) {
        const int f = 4 * g + fi;
        const int rb2 = (f * 16 + n) * 4;
        const float4 w0v = w4[rb2 + (gx ^ 0)];
        const float4 w1v = w4[rb2 + (gx ^ 1)];
        const float4 w2v = w4[rb2 + (gx ^ 2)];
        const float4 w3v = w4[rb2 + (gx ^ 3)];
        float accR = w0v.x*sR0.x + w0v.y*sR0.y + w0v.z*sR0.z + w0v.w*sR0.w
                   + w1v.x*sR1.x + w1v.y*sR1.y + w1v.z*sR1.z + w1v.w*sR1.w
                   + w2v.x*sR2.x + w2v.y*sR2.y + w2v.z*sR2.z + w2v.w*sR2.w
                   + w3v.x*sR3.x + w3v.y*sR3.y + w3v.z*sR3.z + w3v.w*sR3.w;
        float accI = w0v.x*sI0.x + w0v.y*sI0.y + w0v.z*sI0.z + w0v.w*sI0.w
                   + w1v.x*sI1.x + w1v.y*sI1.y + w1v.z*sI1.z + w1v.w*sI1.w
                   + w2v.x*sI2.x + w2v.y*sI2.y + w2v.z*sI2.z + w2v.w*sI2.w
                   + w3v.x*sI3.x + w3v.y*sI3.y + w3v.z*sI3.z + w3v.w*sI3.w;
        if (n == 0) accR += cent[fi];
        *(float2*)&Out[out_base + (f * 16 + n) * 2] = make_float2(accR, accI);
    }
}

extern "C" void kernel_launch(void* const* d_in, const int* in_sizes, int n_in,
                              void* d_out, int out_size, void* d_ws, size_t ws_size,
                              hipStream_t stream) {
    (void)in_sizes; (void)n_in; (void)out_size;
    const float* x  = (const float*)d_in[0];
    const float* ar = (const float*)d_in[1];
    const float* ai = (const float*)d_in[2];
    const float* w  = (const float*)d_in[3];
    const float* wc = (const float*)d_in[4];
    const float* bc = (const float*)d_in[5];
    float* out = (float*)d_out;

    if (ws_size >= (size_t)WS_T6_BYTES) {
        char* wsb = (char*)d_ws;
        hipLaunchKernelGGL(bsh_precompute_gemm, dim3(28), dim3(512), 0, stream,
                           ar, ai, w, wc, bc, (uint4*)wsb);
        hipLaunchKernelGGL(bsh_xp, dim3(245), dim3(512), 0, stream, x, wsb);
        hipLaunchKernelGGL(bsh_gemm_t6, dim3(768), dim3(512), 0, stream,
                           (const char*)wsb, out);
    } else if (ws_size >= (size_t)WS_T3_BYTES) {
        uint4* tb = (uint4*)d_ws;
        hipLaunchKernelGGL(bsh_precompute_gemm, dim3(28), dim3(512), 0, stream,
                           ar, ai, w, wc, bc, tb);
        hipLaunchKernelGGL(bsh_gemm_t3, dim3(2304), dim3(512), 0, stream,
                           x, tb, out);
    } else {
        float* tbl = (float*)d_ws;
        hipLaunchKernelGGL(fb_precompute, dim3(1), dim3(512), 0, stream,
                           ar, ai, w, wc, bc, tbl);
        hipLaunchKernelGGL(fb_kernel, dim3(FB_NBLK), dim3(512), 0, stream,
                           x, tbl, out);
    }
}

// Round 12
// 50.634 us; speedup vs baseline: 1.3692x; 1.3692x over previous
//
#include <hip/hip_runtime.h>

// BSHConv3D as ONE im2col GEMM, round 12: round-10 persistent 3-tile pipeline
// with COUNTED-vmcnt raw barriers (T4). __syncthreads()'s implicit
// s_waitcnt vmcnt(0) was force-draining every store burst at every barrier
// (6/block) -> write pipe bursty. Replace with:
//   asm s_waitcnt vmcnt(6)  (retires the <=3 stage loads; leaves the 6 newest
//   stores in flight)  + sched_barrier(0)  + raw s_barrier.
// Everything else identical to round 10 (51.8 us).
// Tiers: t7 (table+Xp, ~2.23 MB ws) > t3 (229 KB) > fb (24 KB).

typedef _Float16 half8_t __attribute__((ext_vector_type(8)));
typedef float floatx4 __attribute__((ext_vector_type(4)));

#define TB_SLOTS (7 * 32 * 64)                 // 14336 uint4 slots
#define TBL_BYTES (TB_SLOTS * 16)              // 229376
#define XP_OFF   TBL_BYTES
#define XP_BYTES (50 * 50 * 50 * 16)           // 2,000,000
#define BIAS_OFF (XP_OFF + XP_BYTES)
#define WS_T7_BYTES (BIAS_OFF + 16)            // 2,229,392
#define WS_T3_BYTES TBL_BYTES

typedef __attribute__((address_space(1))) const unsigned int gq_t;
typedef __attribute__((address_space(3))) unsigned int lq_t;

__device__ inline unsigned short f2h(float v) {
    return __builtin_bit_cast(unsigned short, (_Float16)v);
}
__device__ inline unsigned pk2(float a, float b) {
    return (unsigned)f2h(a) | ((unsigned)f2h(b) << 16);
}

// ---------------- table precompute (unchanged) ----------------
__global__ __launch_bounds__(512) void bsh_precompute_gemm(
    const float* __restrict__ AR,  // [27,2,16]
    const float* __restrict__ AI,  // [27,2,16]
    const float* __restrict__ Wgt, // [8,16,2,4]
    const float* __restrict__ WC,  // [8,16]
    const float* __restrict__ Bc,  // [16]
    uint4* __restrict__ TB)
{
    int s = blockIdx.x * 512 + threadIdx.x;
    if (s >= TB_SLOTS) return;
    int l = s & 63, ot = (s >> 6) & 31, t = s >> 11;
    int col = 16 * ot + (l & 15);
    int f = col >> 5, n = (col >> 1) & 15, ri = col & 1;
    int dg = (n >= 9) ? 3 : (n >= 4) ? 2 : (n >= 1) ? 1 : 0;
    const float* atom = ri ? AI : AR;
    float vj[8];
    #pragma unroll
    for (int j = 0; j < 8; ++j) {
        int kap = 32 * t + 8 * (l >> 4) + j;
        int k = kap >> 3, c = kap & 7;
        float v = 0.f;
        if (k < 27) {
            float w0 = Wgt[((c * 16 + f) * 2 + 0) * 4 + dg];
            float w1 = Wgt[((c * 16 + f) * 2 + 1) * 4 + dg];
            v = atom[k * 32 + n] * w0 + atom[k * 32 + 16 + n] * w1;
            if (k == 13 && n == 0 && ri == 0) v += WC[c * 16 + f];
        } else {
            if (c == 7 && n == 0 && ri == 0) v = Bc[f];
        }
        vj[j] = v;
    }
    TB[s] = make_uint4(pk2(vj[0], vj[1]), pk2(vj[2], vj[3]),
                       pk2(vj[4], vj[5]), pk2(vj[6], vj[7]));
}

// ---------------- Xp: padded fp16 copy of X (unchanged) ----------------
__global__ __launch_bounds__(512) void bsh_xp(
    const float* __restrict__ X, char* __restrict__ WSB)
{
    int idx = blockIdx.x * 512 + threadIdx.x;
    if (idx == 0)
        *(uint4*)(WSB + BIAS_OFF) = make_uint4(0u, 0u, 0u, 0x3C000000u); // 1.0h at c7
    if (idx >= 125000) return;
    int dd = idx / 2500, rem = idx - dd * 2500;
    int hh = rem / 50, ww = rem - hh * 50;
    unsigned x01 = 0, x23 = 0, x45 = 0, x67 = 0;
    if (dd >= 1 && dd <= 48 && hh >= 1 && hh <= 48 && ww >= 1 && ww <= 48) {
        const float* px = &X[((((dd - 1) * 48) + (hh - 1)) * 48 + (ww - 1)) * 8];
        float4 a = *(const float4*)px;
        float4 b = *(const float4*)(px + 4);
        x01 = pk2(a.x, a.y); x23 = pk2(a.z, a.w);
        x45 = pk2(b.x, b.y); x67 = pk2(b.z, b.w);
    }
    *(uint4*)(WSB + XP_OFF + (size_t)idx * 16) = make_uint4(x01, x23, x45, x67);
}

// ---------------- main GEMM kernel (t7, counted-vmcnt pipeline) ----------------
__global__ __launch_bounds__(512) void bsh_gemm_t7(
    const char* __restrict__ WSB,
    float* __restrict__ Out)       // [110592,512]
{
    // [buf][k28][v48][8ch] fp16 = 21504 B per buffer
    __shared__ __align__(16) _Float16 B_lds[2][28 * 48 * 8];

    const int tid = threadIdx.x;
    const int bid = blockIdx.x;
    const int nb = bid & 1;        // col half (256 outcols)
    const int g3 = (bid >> 1) * 3; // first tile rb of this block's 3

    const uint4* TB   = (const uint4*)WSB;
    const char*  Xp   = WSB + XP_OFF;
    const char*  BIAS = WSB + BIAS_OFF;

    const int lane = tid & 63, cg = tid >> 6;   // 8 waves = 8 col-groups of 32
    const int kg = lane >> 4, lr = lane & 15;

    // ---- A-frags (table): 14 uint4, loaded ONCE for all 3 tiles ----
    const uint4* ap = TB + ((size_t)(nb * 16 + cg * 2) * 64 + lane);
    uint4 af[2][7];
    #pragma unroll
    for (int t = 0; t < 7; ++t) {
        af[0][t] = ap[(size_t)(t * 32 + 0) * 64];
        af[1][t] = ap[(size_t)(t * 32 + 1) * 64];
    }

    // ---- stage h-row (2*hp+hf) of tile rb into B_lds[hf]: <=3 gload_lds ----
    auto stage = [&](int hf, int rb) {
        int d  = rb / 24;
        int hp = rb - 24 * d;
        #pragma unroll
        for (int i = 0; i < 3; ++i) {
            int cell = tid + i * 512;
            if (cell < 1344) {                 // cut at 1344 is wave-aligned
                int k = cell / 48;
                int v = cell - 48 * k;
                const char* src;
                if (k == 27) {
                    src = BIAS;
                } else {
                    int kz = k / 9, r9 = k - 9 * kz;
                    int ky = r9 / 3, kx = r9 - 3 * ky;
                    int dd  = d + kz;              // padded coords
                    int hhp = 2 * hp + hf + ky;
                    int wwp = v + kx;
                    src = Xp + (((size_t)(dd * 50 + hhp) * 50 + wwp) << 4);
                }
                __builtin_amdgcn_global_load_lds(
                    (const gq_t*)src,
                    (lq_t*)&B_lds[hf][cell * 8],
                    16, 0, 0);
            }
        }
    };

    // ---- compute h-row of tile rb from B_lds[hf]: 3 slices, 6 stores total ----
    auto compute = [&](int hf, int rb) {
        int d  = rb / 24;
        int hp = rb - 24 * d;
        const char* bbase = (const char*)&B_lds[hf][0] + kg * 768 + lr * 16;
        #pragma unroll 1
        for (int vt = 0; vt < 3; ++vt) {
            const char* brow = bbase + vt * 256;
            half8_t b[7];
            #pragma unroll
            for (int t = 0; t < 7; ++t)
                b[t] = *(const half8_t*)(brow + t * 3072);

            floatx4 a0 = (floatx4){0.f, 0.f, 0.f, 0.f};
            floatx4 a1 = (floatx4){0.f, 0.f, 0.f, 0.f};
            #pragma unroll
            for (int t = 0; t < 7; ++t)
                a0 = __builtin_amdgcn_mfma_f32_16x16x32_f16(
                         __builtin_bit_cast(half8_t, af[0][t]), b[t], a0, 0, 0, 0);
            #pragma unroll
            for (int t = 0; t < 7; ++t)
                a1 = __builtin_amdgcn_mfma_f32_16x16x32_f16(
                         __builtin_bit_cast(half8_t, af[1][t]), b[t], a1, 0, 0, 0);

            float* ob = Out + (size_t)((d * 48 + 2 * hp + hf) * 48 + vt * 16 + lr) * 512
                            + nb * 256 + cg * 32 + 4 * kg;
            *(floatx4*)ob        = a0;
            *(floatx4*)(ob + 16) = a1;
        }
    };

    // ---- 3-tile pipeline with counted-vmcnt barriers ----
    stage(0, g3);
    asm volatile("s_waitcnt vmcnt(0)" ::: "memory");   // no stores yet
    __builtin_amdgcn_sched_barrier(0);
    __builtin_amdgcn_s_barrier();
    #pragma unroll 1
    for (int ti = 0; ti < 3; ++ti) {
        int rb = g3 + ti;
        stage(1, rb);                   // <=3 loads, in flight under compute(0)
        compute(0, rb);                 // ds_read + MFMA + 6 stores
        // queue (newest last): [stage(1) loads][6 stores] -> vmcnt(6) retires
        // the loads (barrier requirement) but leaves stores in flight.
        asm volatile("s_waitcnt vmcnt(6)" ::: "memory");
        __builtin_amdgcn_sched_barrier(0);
        __builtin_amdgcn_s_barrier();
        if (ti < 2) stage(0, rb + 1);
        compute(1, rb);
        asm volatile("s_waitcnt vmcnt(6)" ::: "memory");
        __builtin_amdgcn_sched_barrier(0);
        __builtin_amdgcn_s_barrier();
    }
}

// ---------------- t3 path (round-8 kernel, table-only ws) ----------------
__global__ __launch_bounds__(512) void bsh_gemm_t3(
    const float* __restrict__ X,
    const uint4* __restrict__ TB,
    float* __restrict__ Out)
{
    __shared__ _Float16 B_lds[96 * 232];

    const int tid = threadIdx.x;
    const int bid = blockIdx.x;
    const int nb = bid & 1;
    const int rb = bid >> 1;
    const int d  = rb / 24;
    const int hp = rb - 24 * d;

    const int lane = tid & 63, cg = tid >> 6;
    const int kg = lane >> 4, lr = lane & 15;

    const uint4* ap = TB + ((size_t)(nb * 16 + cg * 2) * 64 + lane);
    uint4 af[2][7];
    #pragma unroll
    for (int t = 0; t < 7; ++t) {
        af[0][t] = ap[(size_t)(t * 32 + 0) * 64];
        af[1][t] = ap[(size_t)(t * 32 + 1) * 64];
    }

    #pragma unroll
    for (int i = 0; i < 6; ++i) {
        int cell = tid + i * 512;
        if (cell < 2688) {
            int k = cell / 96;
            int v = cell - 96 * k;
            unsigned x01 = 0, x23 = 0, x45 = 0, x67 = 0;
            if (k == 27) {
                x67 = 0x3C000000u;
            } else {
                int kz = k / 9, r9 = k - 9 * kz;
                int ky = r9 / 3, kx = r9 - 3 * ky;
                int hl = (v >= 48) ? 1 : 0;
                int dd = d - 1 + kz;
                int hh = 2 * hp + hl - 1 + ky;
                int ww = v - 48 * hl - 1 + kx;
                if ((unsigned)dd < 48u && (unsigned)hh < 48u && (unsigned)ww < 48u) {
                    const float* px = &X[(((dd * 48 + hh) * 48) + ww) * 8];
                    float4 a = *(const float4*)px;
                    float4 b = *(const float4*)(px + 4);
                    x01 = pk2(a.x, a.y); x23 = pk2(a.z, a.w);
                    x45 = pk2(b.x, b.y); x67 = pk2(b.z, b.w);
                }
            }
            char* wp = (char*)B_lds + v * 464 + k * 16;
            *(uint2*)wp       = make_uint2(x01, x23);
            *(uint2*)(wp + 8) = make_uint2(x45, x67);
        }
    }
    __syncthreads();

    const char* bbase = (const char*)B_lds + lr * 464 + kg * 16;

    #pragma unroll 1
    for (int vt = 0; vt < 6; ++vt) {
        const char* brow = bbase + (size_t)vt * 16 * 464;
        half8_t b[7];
        #pragma unroll
        for (int t = 0; t < 7; ++t)
            b[t] = *(const half8_t*)(brow + 64 * t);

        floatx4 a0 = (floatx4){0.f, 0.f, 0.f, 0.f};
        floatx4 a1 = (floatx4){0.f, 0.f, 0.f, 0.f};
        #pragma unroll
        for (int t = 0; t < 7; ++t)
            a0 = __builtin_amdgcn_mfma_f32_16x16x32_f16(
                     __builtin_bit_cast(half8_t, af[0][t]), b[t], a0, 0, 0, 0);
        #pragma unroll
        for (int t = 0; t < 7; ++t)
            a1 = __builtin_amdgcn_mfma_f32_16x16x32_f16(
                     __builtin_bit_cast(half8_t, af[1][t]), b[t], a1, 0, 0, 0);

        float* ob = Out + (size_t)(rb * 96 + vt * 16 + lr) * 512
                        + nb * 256 + cg * 32 + 4 * kg;
        *(floatx4*)ob        = a0;
        *(floatx4*)(ob + 16) = a1;
    }
}

// ================= fallback path (round-2 kernel, 24 KB ws) =================
#define FB_NBLK (48*48*6)
#define FB_WS_FLOATS 5968

__global__ __launch_bounds__(512) void fb_precompute(
    const float* __restrict__ AR, const float* __restrict__ AI,
    const float* __restrict__ Wgt, const float* __restrict__ WC,
    const float* __restrict__ Bc, float* __restrict__ T)
{
    const int tid = threadIdx.x;
    for (int i = tid; i < 4096; i += 512) {
        int row = i >> 4, f = row >> 4, n = row & 15;
        int pc = (i >> 2) & 3, e = i & 3;
        int chunk = pc ^ (n & 3);
        int cr = chunk * 4 + e, c = cr >> 1, r = cr & 1;
        int dg = (n >= 9) ? 3 : (n >= 4) ? 2 : (n >= 1) ? 1 : 0;
        T[i] = Wgt[c * 128 + f * 8 + r * 4 + dg];
    }
    for (int i = tid; i < 1728; i += 512) {
        int k = i >> 6, n = (i >> 2) & 15, q = i & 3;
        const float* src = (q >> 1) ? AI : AR;
        T[4096 + i] = src[k * 32 + (q & 1) * 16 + n];
    }
    if (tid < 128) T[5824 + tid] = WC[(tid & 7) * 16 + (tid >> 3)];
    if (tid < 16)  T[5952 + tid] = Bc[tid];
}

__device__ inline float4 fb_shfl_xor4(float4 v, int m) {
    return make_float4(__shfl_xor(v.x, m), __shfl_xor(v.y, m),
                       __shfl_xor(v.z, m), __shfl_xor(v.w, m));
}

__global__ __launch_bounds__(512) void fb_kernel(
    const float* __restrict__ X, const float* __restrict__ T,
    float* __restrict__ Out)
{
    __shared__ float cst[FB_WS_FLOATS];
    __shared__ float x_lds[720];

    const int tid = threadIdx.x;
    const int bid = blockIdx.x;
    const int d  = bid / (48 * 6);
    const int r0 = bid - d * (48 * 6);
    const int h  = r0 / 6;
    const int w0 = (r0 - h * 6) * 8;

    {
        const float4* t4 = (const float4*)T;
        float4* c4 = (float4*)cst;
        #pragma unroll
        for (int i = 0; i < 3; ++i) {
            int idx = tid + i * 512;
            if (idx < FB_WS_FLOATS / 4) c4[idx] = t4[idx];
        }
        if (tid < 180) {
            int r3 = tid / 20, rem = tid - r3 * 20;
            int wx = rem >> 1, c0 = (rem & 1) * 4;
            int dz = r3 / 3, dy = r3 - dz * 3;
            int dd = d - 1 + dz, hh = h - 1 + dy, ww = w0 - 1 + wx;
            float4 v = make_float4(0.f, 0.f, 0.f, 0.f);
            if ((unsigned)dd < 48u && (unsigned)hh < 48u && (unsigned)ww < 48u)
                v = *(const float4*)&X[(((dd * 48 + hh) * 48 + ww) * 8) + c0];
            *(float4*)&x_lds[tid * 4] = v;
        }
    }
    __syncthreads();

    const int wave = tid >> 6, lane = tid & 63;
    const int n = lane & 15, g = lane >> 4;
    const float* atoms_lds = cst + 4096;
    const float* wc_lds    = cst + 5824;
    const float* b_lds     = cst + 5952;

    float sr0 = 0, sr1 = 0, sr2 = 0, sr3 = 0;
    float si0 = 0, si1 = 0, si2 = 0, si3 = 0;
    #pragma unroll
    for (int kz = 0; kz < 3; ++kz)
    #pragma unroll
    for (int ky = 0; ky < 3; ++ky)
    #pragma unroll
    for (int kx = 0; kx < 3; ++kx) {
        const int k = (kz * 3 + ky) * 3 + kx;
        const float2 xv = *(const float2*)&x_lds[(((kz * 3 + ky) * 10) + wave + kx) * 8 + 2 * g];
        const float4 a  = *(const float4*)&atoms_lds[k * 64 + n * 4];
        sr0 += xv.x * a.x; sr1 += xv.x * a.y;
        sr2 += xv.y * a.x; sr3 += xv.y * a.y;
        si0 += xv.x * a.z; si1 += xv.x * a.w;
        si2 += xv.y * a.z; si3 += xv.y * a.w;
    }
    const float4 sR0 = make_float4(sr0, sr1, sr2, sr3);
    const float4 sI0 = make_float4(si0, si1, si2, si3);
    const float4 sR1 = fb_shfl_xor4(sR0, 16), sI1 = fb_shfl_xor4(sI0, 16);
    const float4 sR2 = fb_shfl_xor4(sR0, 32), sI2 = fb_shfl_xor4(sI0, 32);
    const float4 sR3 = fb_shfl_xor4(sR1, 32), sI3 = fb_shfl_xor4(sI1, 32);

    float cent[4];
    {
        const int cb = ((1 * 3 + 1) * 10 + wave + 1) * 8;
        const float4 xc0 = *(const float4*)&x_lds[cb];
        const float4 xc1 = *(const float4*)&x_lds[cb + 4];
        #pragma unroll
        for (int fi = 0; fi < 4; ++fi) {
            const int f = 4 * g + fi;
            const float* wcr = &wc_lds[f * 8];
            cent[fi] = b_lds[f]
                + xc0.x * wcr[0] + xc0.y * wcr[1] + xc0.z * wcr[2] + xc0.w * wcr[3]
                + xc1.x * wcr[4] + xc1.y * wcr[5] + xc1.z * wcr[6] + xc1.w * wcr[7];
        }
    }

    const float4* w4 = (const float4*)cst;
    const int gx = g ^ (n & 3);
    const int out_base = ((d * 48 + h) * 48 + (w0 + wave)) * 512;
    #pragma unroll
    for (int fi = 0; fi < 4; ++fi) {
        const int f = 4 * g + fi;
        const int rb2 = (f * 16 + n) * 4;
        const float4 w0v = w4[rb2 + (gx ^ 0)];
        const float4 w1v = w4[rb2 + (gx ^ 1)];
        const float4 w2v = w4[rb2 + (gx ^ 2)];
        const float4 w3v = w4[rb2 + (gx ^ 3)];
        float accR = w0v.x*sR0.x + w0v.y*sR0.y + w0v.z*sR0.z + w0v.w*sR0.w
                   + w1v.x*sR1.x + w1v.y*sR1.y + w1v.z*sR1.z + w1v.w*sR1.w
                   + w2v.x*sR2.x + w2v.y*sR2.y + w2v.z*sR2.z + w2v.w*sR2.w
                   + w3v.x*sR3.x + w3v.y*sR3.y + w3v.z*sR3.z + w3v.w*sR3.w;
        float accI = w0v.x*sI0.x + w0v.y*sI0.y + w0v.z*sI0.z + w0v.w*sI0.w
                   + w1v.x*sI1.x + w1v.y*sI1.y + w1v.z*sI1.z + w1v.w*sI1.w
                   + w2v.x*sI2.x + w2v.y*sI2.y + w2v.z*sI2.z + w2v.w*sI2.w
                   + w3v.x*sI3.x + w3v.y*sI3.y + w3v.z*sI3.z + w3v.w*sI3.w;
        if (n == 0) accR += cent[fi];
        *(float2*)&Out[out_base + (f * 16 + n) * 2] = make_float2(accR, accI);
    }
}

extern "C" void kernel_launch(void* const* d_in, const int* in_sizes, int n_in,
                              void* d_out, int out_size, void* d_ws, size_t ws_size,
                              hipStream_t stream) {
    (void)in_sizes; (void)n_in; (void)out_size;
    const float* x  = (const float*)d_in[0];
    const float* ar = (const float*)d_in[1];
    const float* ai = (const float*)d_in[2];
    const float* w  = (const float*)d_in[3];
    const float* wc = (const float*)d_in[4];
    const float* bc = (const float*)d_in[5];
    float* out = (float*)d_out;

    if (ws_size >= (size_t)WS_T7_BYTES) {
        char* wsb = (char*)d_ws;
        hipLaunchKernelGGL(bsh_precompute_gemm, dim3(28), dim3(512), 0, stream,
                           ar, ai, w, wc, bc, (uint4*)wsb);
        hipLaunchKernelGGL(bsh_xp, dim3(245), dim3(512), 0, stream, x, wsb);
        hipLaunchKernelGGL(bsh_gemm_t7, dim3(768), dim3(512), 0, stream,
                           (const char*)wsb, out);
    } else if (ws_size >= (size_t)WS_T3_BYTES) {
        uint4* tb = (uint4*)d_ws;
        hipLaunchKernelGGL(bsh_precompute_gemm, dim3(28), dim3(512), 0, stream,
                           ar, ai, w, wc, bc, tb);
        hipLaunchKernelGGL(bsh_gemm_t3, dim3(2304), dim3(512), 0, stream,
                           x, tb, out);
    } else {
        float* tbl = (float*)d_ws;
        hipLaunchKernelGGL(fb_precompute, dim3(1), dim3(512), 0, stream,
                           ar, ai, w, wc, bc, tbl);
        hipLaunchKernelGGL(fb_kernel, dim3(FB_NBLK), dim3(512), 0, stream,
                           x, tbl, out);
    }
}